// Round 1
// 4275.296 us; speedup vs baseline: 2.2446x; 2.2446x over previous
//
#include <hip/hip_runtime.h>

#define BATCH 64
#define SEQT  512
#define DIM   1024

#define JB   32                 // j-rows per block
#define BB   8                  // batches per block
#define NJG  (DIM / JB)         // 32 j-groups (column size)
#define NBG  (BATCH / BB)       // 8 independent columns
#define NBLK (NJG * NBG)        // 256 blocks
#define NTHR 512
#define UPITCH 34               // 8B-aligned rows, (2k+c)%32 banks -> ~2-way (free)

// dynamic LDS carve-up (floats)
#define LDS_U    (DIM * UPITCH)          // 139264 B
#define LDS_RED  (8 * 256)               // 8192 B
#define LDS_VAL  (256)                   // 1024 B
#define LDS_H    (8 * 2 * 128)           // 8192 B: 8 waves x 2 bufs x 128 floats
#define LDS_BYTES ((LDS_U + LDS_RED + LDS_VAL + LDS_H) * 4)   // 156672 < 163840

typedef unsigned long long ull;

union F2U {
    ull u;
    float f[2];
};

// ---------------------------------------------------------------------------
// Phase 1: wx = x @ W_w^T + W_b  (fp32, 64x64 tile, BK=16, 4x4 micro-tile)
// ---------------------------------------------------------------------------
__global__ __launch_bounds__(256) void gemm_wx(const float* __restrict__ x,
                                               const float* __restrict__ Ww,
                                               const float* __restrict__ Wb,
                                               float* __restrict__ out) {
    __shared__ float As[16][64];
    __shared__ float Bs[16][64];

    const int tid = threadIdx.x;
    const int nb = blockIdx.x & 15;
    const int mb = blockIdx.x >> 4;
    const int m0 = mb * 64, n0 = nb * 64;
    const int tx = tid & 15, ty = tid >> 4;
    const int r0 = ty * 4, c0 = tx * 4;

    float acc[4][4] = {};

    const int lrow = tid >> 2;
    const int lk = (tid & 3) * 4;
    const float* xa = x + (size_t)(m0 + lrow) * DIM + lk;
    const float* wa = Ww + (size_t)(n0 + lrow) * DIM + lk;

    for (int kt = 0; kt < DIM / 16; ++kt) {
        float4 av = *(const float4*)xa;
        float4 bv = *(const float4*)wa;
        __syncthreads();
        As[lk + 0][lrow] = av.x; As[lk + 1][lrow] = av.y;
        As[lk + 2][lrow] = av.z; As[lk + 3][lrow] = av.w;
        Bs[lk + 0][lrow] = bv.x; Bs[lk + 1][lrow] = bv.y;
        Bs[lk + 2][lrow] = bv.z; Bs[lk + 3][lrow] = bv.w;
        __syncthreads();
#pragma unroll
        for (int kk = 0; kk < 16; ++kk) {
            float4 a = *(const float4*)&As[kk][r0];
            float4 b = *(const float4*)&Bs[kk][c0];
            acc[0][0] += a.x * b.x; acc[0][1] += a.x * b.y; acc[0][2] += a.x * b.z; acc[0][3] += a.x * b.w;
            acc[1][0] += a.y * b.x; acc[1][1] += a.y * b.y; acc[1][2] += a.y * b.z; acc[1][3] += a.y * b.w;
            acc[2][0] += a.z * b.x; acc[2][1] += a.z * b.y; acc[2][2] += a.z * b.z; acc[2][3] += a.z * b.w;
            acc[3][0] += a.w * b.x; acc[3][1] += a.w * b.y; acc[3][2] += a.w * b.z; acc[3][3] += a.w * b.w;
        }
        xa += 16; wa += 16;
    }

    float4 wb = *(const float4*)(Wb + n0 + c0);
#pragma unroll
    for (int i = 0; i < 4; ++i) {
        float4 o;
        o.x = acc[i][0] + wb.x; o.y = acc[i][1] + wb.y;
        o.z = acc[i][2] + wb.z; o.w = acc[i][3] + wb.w;
        *(float4*)(out + (size_t)(m0 + r0 + i) * DIM + n0 + c0) = o;
    }
}

// ---------------------------------------------------------------------------
// Phase 2: persistent cooperative scan, U-slice resident in LDS.
// Round 5:
//  - h loads de-duplicated 8x: round 4 had every jt-group load identical h
//    (64 x 8B atomic loads/thread = 64 MB of MALL atomics per step; the MALL
//    op rate was THE bottleneck: 16.9us/step at ~0 VALUBusy). Now each wave
//    loads only its disjoint kslot slice with zero redundancy (8 x 8B
//    atomics/thread = 8 MB/step) and stages it in a PRIVATE per-wave LDS
//    region. Same-wave DS ops execute in order -> no extra barriers at all.
//  - staging reads are ds_read_b128, 8 distinct 16B slots + 8-way broadcast
//    per wave -> conflict-free.
//  - poll narrowed to 32 lanes (lanes 32-63 were loading duplicate flags).
//  - publish via RETURNING atomic exchanges + waitcnt-then-flag (unchanged,
//    correctness anchor from round 4).
// ---------------------------------------------------------------------------
__global__ __launch_bounds__(NTHR, 1) void rnn_scan3(
    const float* __restrict__ Uw,   // [j][k] original layout
    const float* __restrict__ Ub,
    const float* __restrict__ bias,
    float* __restrict__ out,        // [B][T][D] holds wx, overwritten; +hT tail
    float* __restrict__ h0,         // [D][64]
    float* __restrict__ h1,         // [D][64]
    unsigned* __restrict__ bar) {   // flags: [bg][jg] spaced 64B, zeroed
    extern __shared__ float lds[];
    float* Ulds = lds;                    // [DIM][UPITCH], Ulds[k][c]=Uw[j0+c][k]
    float* red  = lds + LDS_U;            // [8 waves][256]
    float* val  = red + LDS_RED;          // [256]
    float* hbuf = val + LDS_VAL;          // [8 waves][2 bufs][4 i][4 ksl][8 b]

    const int tid = threadIdx.x;
    const int bg = blockIdx.x & 7;
    const int jg = blockIdx.x >> 3;
    const int j0 = jg * JB;
    const int b0 = bg * BB;

    // one-time LDS fill of this block's U-slice (transposed to [k][j])
    {
        int c = tid & 31;
        int kc = (tid >> 5) << 6;  // 16 chunks of 64 k
        const float* src = Uw + (size_t)(j0 + c) * DIM + kc;
#pragma unroll
        for (int i = 0; i < 16; ++i) {
            float4 v = *(const float4*)(src + i * 4);
            int k = kc + i * 4;
            Ulds[(k + 0) * UPITCH + c] = v.x;
            Ulds[(k + 1) * UPITCH + c] = v.y;
            Ulds[(k + 2) * UPITCH + c] = v.z;
            Ulds[(k + 3) * UPITCH + c] = v.w;
        }
    }

    float cst = 0.f;
    if (tid < 256) {
        int jl = tid & 31;
        cst = Ub[j0 + jl] + bias[j0 + jl];
    }
    __syncthreads();

    const int ksl = tid & 3;
    const int jt  = (tid >> 2) & 7;
    const int bt  = (tid >> 5) & 1;
    const int w   = tid >> 6;
    const int kslot = (w << 2) | ksl;   // 0..31

    // staging roles: lane = (ksl, ilL, bpL); per-wave data is the disjoint
    // k subset {kslot + 32*i} x 8 batches -> zero-redundancy loads.
    const int ilL = jt & 3;             // (tid>>2)&3: i-slot within chunk
    const int bpL = (tid >> 4) & 3;     // ull (b-pair) within 8-batch slice

    unsigned* myflag = bar + (size_t)bg * 512 + (size_t)jg * 16;

    const float* uw_p0 = Ulds + (size_t)kslot * UPITCH + jt * 4;
    // global ull index of this lane's chunk-0 load: h[k=kslot+32*ilL][b-pair]
    const size_t lbase = (size_t)(kslot + 32 * ilL) * 32 + (b0 >> 1) + bpL;

    float* hw0 = hbuf + w * 256 + (ilL * 4 + ksl) * 8 + bpL * 2;   // write slot
    const float* hr0 = hbuf + w * 256 + ksl * 8 + bt * 4;          // read base

    ull junk = 0;

    for (int t = 0; t < SEQT; ++t) {
        const float* hc = (t & 1) ? h1 : h0;
        float* hn = (t & 1) ? h0 : h1;

        // issue ALL of this step's h loads up front (depth-8 pipelined);
        // 1 ull per lane per chunk, unique across the block.
        const ull* hcu = (const ull*)hc;
        ull ld[8];
#pragma unroll
        for (int ci = 0; ci < 8; ++ci)
            ld[ci] = __hip_atomic_load(hcu + lbase + (size_t)ci * 4096,
                                       __ATOMIC_RELAXED, __HIP_MEMORY_SCOPE_AGENT);

        // prefetch this step's wx (latency hidden behind the k-loop)
        float wxv = 0.f;
        size_t oidx = 0;
        if (tid < 256) {
            int jl = tid & 31, bl = tid >> 5;
            oidx = ((size_t)(b0 + bl) * SEQT + t) * DIM + (j0 + jl);
            wxv = out[oidx];
        }

        float acc[4][4] = {};   // [jj][bb]
        const float* up = uw_p0;

#pragma unroll
        for (int ci = 0; ci < 8; ++ci) {
            // stage this wave's chunk into its private LDS region.
            // same-wave DS ops execute in order -> no barrier needed; the
            // double buffer lets the compiler hoist the next write over
            // this chunk's reads.
            *(ull*)(hw0 + (ci & 1) * 128) = ld[ci];
            const float* hsrc = hr0 + (ci & 1) * 128;
#pragma unroll
            for (int j = 0; j < 4; ++j) {   // i = 4*ci + j, k = kslot + 32*i
                float2 ua = *(const float2*)up;
                float2 ub = *(const float2*)(up + 2);
                float4 h4 = *(const float4*)(hsrc + j * 32);
                acc[0][0] += ua.x * h4.x; acc[0][1] += ua.x * h4.y; acc[0][2] += ua.x * h4.z; acc[0][3] += ua.x * h4.w;
                acc[1][0] += ua.y * h4.x; acc[1][1] += ua.y * h4.y; acc[1][2] += ua.y * h4.z; acc[1][3] += ua.y * h4.w;
                acc[2][0] += ub.x * h4.x; acc[2][1] += ub.x * h4.y; acc[2][2] += ub.x * h4.z; acc[2][3] += ub.x * h4.w;
                acc[3][0] += ub.y * h4.x; acc[3][1] += ub.y * h4.y; acc[3][2] += ub.y * h4.z; acc[3][3] += ub.y * h4.w;
                up += 32 * UPITCH;
            }
        }

        // reduce the 4 in-wave k-slots (lane bits 0,1)
#pragma unroll
        for (int jj = 0; jj < 4; ++jj)
#pragma unroll
            for (int bb = 0; bb < 4; ++bb) {
                float v = acc[jj][bb];
                v += __shfl_xor(v, 1, 64);
                v += __shfl_xor(v, 2, 64);
                acc[jj][bb] = v;
            }
        if (ksl == 0) {
#pragma unroll
            for (int jj = 0; jj < 4; ++jj)
#pragma unroll
                for (int bb = 0; bb < 4; ++bb)
                    red[w * 256 + (bt * 4 + bb) * 32 + jt * 4 + jj] = acc[jj][bb];
        }
        __syncthreads();

        if (tid < 256) {  // cross-wave reduce + tanh + out write (j-fast)
            float s = 0.f;
#pragma unroll
            for (int ww = 0; ww < 8; ++ww) s += red[ww * 256 + tid];
            float v = tanhf(wxv + s + cst);
            out[oidx] = v;
            val[tid] = v;
            if (t == SEQT - 1)
                out[(size_t)BATCH * SEQT * DIM + (size_t)(b0 + (tid >> 5)) * DIM + (j0 + (tid & 31))] = v;
        }
        __syncthreads();

        if (tid < 128) {  // publish h [j][b] as returning 8B exchanges
            int jl = tid >> 2, m = tid & 3;
            F2U p;
            p.f[0] = val[(2 * m + 0) * 32 + jl];
            p.f[1] = val[(2 * m + 1) * 32 + jl];
            ull old = __hip_atomic_exchange(
                (ull*)(hn + (size_t)(j0 + jl) * BATCH + b0 + 2 * m),
                p.u, __ATOMIC_RELAXED, __HIP_MEMORY_SCOPE_AGENT);
            junk ^= old;  // force returning form; consumed after the loop
        }

        if (t < SEQT - 1) {
            __builtin_amdgcn_s_waitcnt(0);  // exchanges acked AT the coherent point
            __syncthreads();                // whole block's publishes visible
            if (tid == 0)
                __hip_atomic_store(myflag, (unsigned)(t + 1),
                                   __ATOMIC_RELAXED, __HIP_MEMORY_SCOPE_AGENT);
            if (tid < 32) {                 // 32 lanes poll the 32 producer flags
                unsigned want = (unsigned)(t + 1);
                unsigned* fp = bar + (size_t)bg * 512 + (size_t)tid * 16;
                unsigned f;
                do {
                    f = __hip_atomic_load(fp, __ATOMIC_RELAXED, __HIP_MEMORY_SCOPE_AGENT);
                } while (__ballot(f < want));
            }
            __syncthreads();
        }
    }

    // impossible (NaN-pair pattern tanh can never produce) — keeps the
    // exchange returns live so vmcnt acks are real coherent-point acks.
    if (junk == 0xFFF00001FFF00002ULL) out[0] = -1.0f;
}

// ---------------------------------------------------------------------------
extern "C" void kernel_launch(void* const* d_in, const int* in_sizes, int n_in,
                              void* d_out, int out_size, void* d_ws, size_t ws_size,
                              hipStream_t stream) {
    const float* x    = (const float*)d_in[0];
    const float* W_w  = (const float*)d_in[1];
    const float* W_b  = (const float*)d_in[2];
    const float* U_w  = (const float*)d_in[3];
    const float* U_b  = (const float*)d_in[4];
    const float* bias = (const float*)d_in[5];
    float* out = (float*)d_out;

    // ws: [0,64K) flags ; [64K, +256K) h0 ; then h1
    unsigned* bar = (unsigned*)d_ws;
    float* h0 = (float*)((char*)d_ws + 65536);
    float* h1 = h0 + (size_t)DIM * BATCH;

    hipMemsetAsync(d_ws, 0, 65536 + 2 * (size_t)DIM * BATCH * sizeof(float), stream);

    gemm_wx<<<dim3((32768 / 64) * (DIM / 64)), dim3(256), 0, stream>>>(x, W_w, W_b, out);

    static bool attr_done = false;
    if (!attr_done) {
        hipFuncSetAttribute((const void*)rnn_scan3,
                            hipFuncAttributeMaxDynamicSharedMemorySize, LDS_BYTES);
        attr_done = true;
    }

    void* args[] = {(void*)&U_w, (void*)&U_b, (void*)&bias,
                    (void*)&out, (void*)&h0, (void*)&h1, (void*)&bar};
    hipLaunchCooperativeKernel((void*)rnn_scan3, dim3(NBLK), dim3(NTHR), args,
                               LDS_BYTES, stream);
}

// Round 3
// 4042.274 us; speedup vs baseline: 2.3740x; 1.0576x over previous
//
#include <hip/hip_runtime.h>

#define BATCH 64
#define SEQT  512
#define DIM   1024

#define JB   32                 // j-rows per block
#define BB   8                  // batches per block
#define NJG  (DIM / JB)         // 32 j-groups (column size)
#define NBG  (BATCH / BB)       // 8 independent columns
#define NBLK (NJG * NBG)        // 256 blocks
#define NTHR 512
#define UPITCH 34               // 8B-aligned rows, (2k+c)%32 banks -> ~2-way (free)

// dynamic LDS carve-up (floats)
#define LDS_U    (DIM * UPITCH)          // 139264 B
#define LDS_RED  (8 * 256)               // 8192 B
#define LDS_VAL  (256)                   // 1024 B
#define LDS_H    (8 * 256)               // 8192 B: 8 waves x 256 floats (1KB chunk each)
#define LDS_BYTES ((LDS_U + LDS_RED + LDS_VAL + LDS_H) * 4)   // 156672 < 163840

typedef unsigned long long ull;
typedef float f4 __attribute__((ext_vector_type(4)));

union F2U {
    ull u;
    float f[2];
};

// ---------------------------------------------------------------------------
// Phase 1: wx = x @ W_w^T + W_b  (fp32, 64x64 tile, BK=16, 4x4 micro-tile)
// ---------------------------------------------------------------------------
__global__ __launch_bounds__(256) void gemm_wx(const float* __restrict__ x,
                                               const float* __restrict__ Ww,
                                               const float* __restrict__ Wb,
                                               float* __restrict__ out) {
    __shared__ float As[16][64];
    __shared__ float Bs[16][64];

    const int tid = threadIdx.x;
    const int nb = blockIdx.x & 15;
    const int mb = blockIdx.x >> 4;
    const int m0 = mb * 64, n0 = nb * 64;
    const int tx = tid & 15, ty = tid >> 4;
    const int r0 = ty * 4, c0 = tx * 4;

    float acc[4][4] = {};

    const int lrow = tid >> 2;
    const int lk = (tid & 3) * 4;
    const float* xa = x + (size_t)(m0 + lrow) * DIM + lk;
    const float* wa = Ww + (size_t)(n0 + lrow) * DIM + lk;

    for (int kt = 0; kt < DIM / 16; ++kt) {
        float4 av = *(const float4*)xa;
        float4 bv = *(const float4*)wa;
        __syncthreads();
        As[lk + 0][lrow] = av.x; As[lk + 1][lrow] = av.y;
        As[lk + 2][lrow] = av.z; As[lk + 3][lrow] = av.w;
        Bs[lk + 0][lrow] = bv.x; Bs[lk + 1][lrow] = bv.y;
        Bs[lk + 2][lrow] = bv.z; Bs[lk + 3][lrow] = bv.w;
        __syncthreads();
#pragma unroll
        for (int kk = 0; kk < 16; ++kk) {
            float4 a = *(const float4*)&As[kk][r0];
            float4 b = *(const float4*)&Bs[kk][c0];
            acc[0][0] += a.x * b.x; acc[0][1] += a.x * b.y; acc[0][2] += a.x * b.z; acc[0][3] += a.x * b.w;
            acc[1][0] += a.y * b.x; acc[1][1] += a.y * b.y; acc[1][2] += a.y * b.z; acc[1][3] += a.y * b.w;
            acc[2][0] += a.z * b.x; acc[2][1] += a.z * b.y; acc[2][2] += a.z * b.z; acc[2][3] += a.z * b.w;
            acc[3][0] += a.w * b.x; acc[3][1] += a.w * b.y; acc[3][2] += a.w * b.z; acc[3][3] += a.w * b.w;
        }
        xa += 16; wa += 16;
    }

    float4 wb = *(const float4*)(Wb + n0 + c0);
#pragma unroll
    for (int i = 0; i < 4; ++i) {
        float4 o;
        o.x = acc[i][0] + wb.x; o.y = acc[i][1] + wb.y;
        o.z = acc[i][2] + wb.z; o.w = acc[i][3] + wb.w;
        *(float4*)(out + (size_t)(m0 + r0 + i) * DIM + n0 + c0) = o;
    }
}

// ---------------------------------------------------------------------------
// Phase 2: persistent cooperative scan, U-slice resident in LDS.
// Round 7 (round 6's L2-scope gamble failed -> reverted to the PROVEN round-5
// MALL protocol everywhere; only safe, incremental changes):
//  - h relaid out column-contiguous h[bg][k][8]: each lane's slice is 4
//    contiguous 16B pieces -> 4 x global_load_dwordx4 sc0 sc1 (cache-bypass,
//    superset of agent-scope bits; loads issue only AFTER flags prove all
//    publishes MALL-acked, so no concurrent writers -> plain wide loads are
//    safe).  MALL load ops halve: 1.05M -> 0.52M per step.
//  - per-wave flags: the two publishing waves each waitcnt-ack their OWN
//    swaps and store their OWN flag (wave-local chain, no all-thread waitcnt
//    + barrier before the flag).  Wave 0 polls all 64 column flags; one
//    barrier releases the block.  4 barriers/step -> 3.
//  - per-wave swizzled LDS staging: writes spread 8 addrs/bank-quad
//    (minimum-pass), reads are 8-addr x 8-way broadcast (conflict-free).
//    Cross-lane LDS write->read ordering fenced with asm memory barriers
//    (compiler may not reorder DS ops it can't prove aliasing for).
//  - publish via RETURNING atomic exchanges + waitcnt-then-flag (unchanged
//    correctness anchor from rounds 4-5).
// ---------------------------------------------------------------------------
__global__ __launch_bounds__(NTHR, 1) void rnn_scan3(
    const float* __restrict__ Uw,   // [j][k] original layout
    const float* __restrict__ Ub,
    const float* __restrict__ bias,
    float* __restrict__ out,        // [B][T][D] holds wx, overwritten; +hT tail
    float* __restrict__ h0,         // [bg][k][8] column-contiguous
    float* __restrict__ h1,         // [bg][k][8]
    unsigned* __restrict__ bar) {   // flags: [bg][jg*2+pubwave] spaced 64B, zeroed
    extern __shared__ float lds[];
    float* Ulds = lds;                    // [DIM][UPITCH], Ulds[k][c]=Uw[j0+c][k]
    float* red  = lds + LDS_U;            // [8 waves][256]
    float* val  = red + LDS_RED;          // [256]
    float* hbuf = val + LDS_VAL;          // [8 waves][256] single chunk buffer

    const int tid = threadIdx.x;
    const int bg = blockIdx.x & 7;
    const int jg = blockIdx.x >> 3;
    const int j0 = jg * JB;
    const int b0 = bg * BB;

    // one-time LDS fill of this block's U-slice (transposed to [k][j])
    {
        int c = tid & 31;
        int kc = (tid >> 5) << 6;  // 16 chunks of 64 k
        const float* src = Uw + (size_t)(j0 + c) * DIM + kc;
#pragma unroll
        for (int i = 0; i < 16; ++i) {
            float4 v = *(const float4*)(src + i * 4);
            int k = kc + i * 4;
            Ulds[(k + 0) * UPITCH + c] = v.x;
            Ulds[(k + 1) * UPITCH + c] = v.y;
            Ulds[(k + 2) * UPITCH + c] = v.z;
            Ulds[(k + 3) * UPITCH + c] = v.w;
        }
    }

    float cst = 0.f;
    if (tid < 256) {
        int jl = tid & 31;
        cst = Ub[j0 + jl] + bias[j0 + jl];
    }
    __syncthreads();

    const int ksl = tid & 3;
    const int jt  = (tid >> 2) & 7;
    const int bt  = (tid >> 5) & 1;
    const int w   = tid >> 6;
    const int kslot = (w << 2) | ksl;   // 0..31

    const float* uw_p0 = Ulds + (size_t)kslot * UPITCH + jt * 4;
    const size_t colf = (size_t)bg * 8192;               // column float offset
    // lane's chunk-0 load: h_col[k = kslot + 32*jt][bt*4 ..], chunk stride 2048 floats
    const size_t lf0 = (size_t)kslot * 8 + (size_t)jt * 256 + bt * 4;
    // swizzled staging slot (write): row jt, 16B slot (ksl*8+bt*4+jt*4)&31
    float* hstg = hbuf + w * 256 + jt * 32 + ((ksl * 8 + bt * 4 + jt * 4) & 31);
    const float* wbase = hbuf + w * 256;
    unsigned* flagbase = bar + (size_t)bg * 1024;        // 4KB per column

    ull junk = 0;

    for (int t = 0; t < SEQT; ++t) {
        const float* hc_col = ((t & 1) ? h1 : h0) + colf;
        float* hn_col = ((t & 1) ? h0 : h1) + colf;

        // prefetch this step's wx early (latency hidden behind k-loop)
        float wxv = 0.f;
        size_t oidx = 0;
        if (tid < 256) {
            int jl = tid & 31, bl = tid >> 5;
            oidx = ((size_t)(b0 + bl) * SEQT + t) * DIM + (j0 + jl);
            wxv = out[oidx];
        }

        // 4 x 16B bypass loads: the lane's whole k-slice, zero redundancy
        const float* hp = hc_col + lf0;
        f4 hv0, hv1, hv2, hv3;
        asm volatile("global_load_dwordx4 %0, %1, off sc0 sc1" : "=v"(hv0) : "v"(hp));
        asm volatile("global_load_dwordx4 %0, %1, off sc0 sc1" : "=v"(hv1) : "v"(hp + 2048));
        asm volatile("global_load_dwordx4 %0, %1, off sc0 sc1" : "=v"(hv2) : "v"(hp + 4096));
        asm volatile("global_load_dwordx4 %0, %1, off sc0 sc1" : "=v"(hv3) : "v"(hp + 6144));
        asm volatile("s_waitcnt vmcnt(0)"
                     : "+v"(hv0), "+v"(hv1), "+v"(hv2), "+v"(hv3)
                     :: "memory");
        __builtin_amdgcn_sched_barrier(0);

        float acc[4][4] = {};   // [jj][bb]
        const float* up = uw_p0;

#pragma unroll
        for (int li = 0; li < 4; ++li) {      // chunk li covers i = 8*li .. 8*li+7
            f4 hv = (li == 0) ? hv0 : (li == 1) ? hv1 : (li == 2) ? hv2 : hv3;
            asm volatile("" ::: "memory");    // order: prior chunk's reads before this write
            *(f4*)hstg = hv;                  // conflict-free-minimum wave write
            asm volatile("" ::: "memory");    // order: write before this chunk's reads
#pragma unroll
            for (int j = 0; j < 8; ++j) {     // i = 8*li + j
                float2 ua = *(const float2*)up;
                float2 ub = *(const float2*)(up + 2);
                f4 h4 = *(const f4*)(wbase + j * 32 + ((ksl * 8 + bt * 4 + j * 4) & 31));
                acc[0][0] += ua.x * h4.x; acc[0][1] += ua.x * h4.y; acc[0][2] += ua.x * h4.z; acc[0][3] += ua.x * h4.w;
                acc[1][0] += ua.y * h4.x; acc[1][1] += ua.y * h4.y; acc[1][2] += ua.y * h4.z; acc[1][3] += ua.y * h4.w;
                acc[2][0] += ub.x * h4.x; acc[2][1] += ub.x * h4.y; acc[2][2] += ub.x * h4.z; acc[2][3] += ub.x * h4.w;
                acc[3][0] += ub.y * h4.x; acc[3][1] += ub.y * h4.y; acc[3][2] += ub.y * h4.z; acc[3][3] += ub.y * h4.w;
                up += 32 * UPITCH;
            }
        }

        // reduce the 4 in-wave k-slots (lane bits 0,1)
#pragma unroll
        for (int jj = 0; jj < 4; ++jj)
#pragma unroll
            for (int bb = 0; bb < 4; ++bb) {
                float v = acc[jj][bb];
                v += __shfl_xor(v, 1, 64);
                v += __shfl_xor(v, 2, 64);
                acc[jj][bb] = v;
            }
        if (ksl == 0) {
#pragma unroll
            for (int jj = 0; jj < 4; ++jj)
#pragma unroll
                for (int bb = 0; bb < 4; ++bb)
                    red[w * 256 + (bt * 4 + bb) * 32 + jt * 4 + jj] = acc[jj][bb];
        }
        __syncthreads();   // A

        if (tid < 256) {  // cross-wave reduce + tanh + out write (j-fast)
            float s = 0.f;
#pragma unroll
            for (int ww = 0; ww < 8; ++ww) s += red[ww * 256 + tid];
            float v = tanhf(wxv + s + cst);
            out[oidx] = v;
            val[tid] = v;
            if (t == SEQT - 1)
                out[(size_t)BATCH * SEQT * DIM + (size_t)(b0 + (tid >> 5)) * DIM + (j0 + (tid & 31))] = v;
        }
        __syncthreads();   // B

        if (tid < 128) {  // publish h_col[k][8] as returning 8B exchanges (waves 0,1)
            int jl = tid >> 2, m = tid & 3;
            F2U p;
            p.f[0] = val[(2 * m + 0) * 32 + jl];
            p.f[1] = val[(2 * m + 1) * 32 + jl];
            ull old = __hip_atomic_exchange(
                (ull*)hn_col + (size_t)(j0 + jl) * 4 + m,
                p.u, __ATOMIC_RELAXED, __HIP_MEMORY_SCOPE_AGENT);
            junk ^= old;  // force returning form; consumed after the loop
        }

        if (t < SEQT - 1) {
            if (tid < 128) {
                // wave-local: this wave's exchanges acked AT the coherent point,
                // then this wave's own flag (no block-wide join needed).
                __builtin_amdgcn_s_waitcnt(0);
                if ((tid & 63) == 0)
                    __hip_atomic_store(flagbase + ((size_t)jg * 2 + (tid >> 6)) * 16,
                                       (unsigned)(t + 1),
                                       __ATOMIC_RELAXED, __HIP_MEMORY_SCOPE_AGENT);
            }
            if (tid < 64) {   // wave 0 polls all 64 producer-wave flags of the column
                unsigned want = (unsigned)(t + 1);
                unsigned* fp = flagbase + (size_t)tid * 16;
                unsigned f;
                do {
                    f = __hip_atomic_load(fp, __ATOMIC_RELAXED, __HIP_MEMORY_SCOPE_AGENT);
                } while (__ballot(f < want));
            }
            __syncthreads();   // C — releases all waves into step t+1 loads
        }
    }

    // impossible (NaN-pair pattern tanh can never produce) — keeps the
    // exchange returns live so vmcnt acks are real coherent-point acks.
    if (junk == 0xFFF00001FFF00002ULL) out[0] = -1.0f;
}

// ---------------------------------------------------------------------------
extern "C" void kernel_launch(void* const* d_in, const int* in_sizes, int n_in,
                              void* d_out, int out_size, void* d_ws, size_t ws_size,
                              hipStream_t stream) {
    const float* x    = (const float*)d_in[0];
    const float* W_w  = (const float*)d_in[1];
    const float* W_b  = (const float*)d_in[2];
    const float* U_w  = (const float*)d_in[3];
    const float* U_b  = (const float*)d_in[4];
    const float* bias = (const float*)d_in[5];
    float* out = (float*)d_out;

    // ws: [0,64K) flags ; [64K, +256K) h0 ; then h1
    unsigned* bar = (unsigned*)d_ws;
    float* h0 = (float*)((char*)d_ws + 65536);
    float* h1 = h0 + (size_t)DIM * BATCH;

    hipMemsetAsync(d_ws, 0, 65536 + 2 * (size_t)DIM * BATCH * sizeof(float), stream);

    gemm_wx<<<dim3((32768 / 64) * (DIM / 64)), dim3(256), 0, stream>>>(x, W_w, W_b, out);

    static bool attr_done = false;
    if (!attr_done) {
        hipFuncSetAttribute((const void*)rnn_scan3,
                            hipFuncAttributeMaxDynamicSharedMemorySize, LDS_BYTES);
        attr_done = true;
    }

    void* args[] = {(void*)&U_w, (void*)&U_b, (void*)&bias,
                    (void*)&out, (void*)&h0, (void*)&h1, (void*)&bar};
    hipLaunchCooperativeKernel((void*)rnn_scan3, dim3(NBLK), dim3(NTHR), args,
                               LDS_BYTES, stream);
}

// Round 4
// 3890.852 us; speedup vs baseline: 2.4664x; 1.0389x over previous
//
#include <hip/hip_runtime.h>

#define BATCH 64
#define SEQT  512
#define DIM   1024

#define JB   32                 // j-rows per block
#define BB   8                  // batches per block
#define NJG  (DIM / JB)         // 32 j-groups (column size)
#define NBG  (BATCH / BB)       // 8 independent columns
#define NBLK (NJG * NBG)        // 256 blocks
#define NTHR 512
#define UPITCH 34               // 8B-aligned rows, (2k+c)%32 banks -> ~2-way (free)

// dynamic LDS carve-up (floats)
#define LDS_U    (DIM * UPITCH)          // 139264 B
#define LDS_RED  (8 * 256)               // 8192 B
#define LDS_VAL  (256)                   // 1024 B
#define LDS_H    (8 * 256)               // 8192 B: 8 waves x 256 floats (1KB chunk each)
#define LDS_BYTES ((LDS_U + LDS_RED + LDS_VAL + LDS_H) * 4)   // 156672 < 163840

typedef unsigned long long ull;
typedef float f4 __attribute__((ext_vector_type(4)));

union F2U {
    ull u;
    float f[2];
};

// ---------------------------------------------------------------------------
// Phase 1: wx = x @ W_w^T + W_b  (fp32, 64x64 tile, BK=16, 4x4 micro-tile)
// ---------------------------------------------------------------------------
__global__ __launch_bounds__(256) void gemm_wx(const float* __restrict__ x,
                                               const float* __restrict__ Ww,
                                               const float* __restrict__ Wb,
                                               float* __restrict__ out) {
    __shared__ float As[16][64];
    __shared__ float Bs[16][64];

    const int tid = threadIdx.x;
    const int nb = blockIdx.x & 15;
    const int mb = blockIdx.x >> 4;
    const int m0 = mb * 64, n0 = nb * 64;
    const int tx = tid & 15, ty = tid >> 4;
    const int r0 = ty * 4, c0 = tx * 4;

    float acc[4][4] = {};

    const int lrow = tid >> 2;
    const int lk = (tid & 3) * 4;
    const float* xa = x + (size_t)(m0 + lrow) * DIM + lk;
    const float* wa = Ww + (size_t)(n0 + lrow) * DIM + lk;

    for (int kt = 0; kt < DIM / 16; ++kt) {
        float4 av = *(const float4*)xa;
        float4 bv = *(const float4*)wa;
        __syncthreads();
        As[lk + 0][lrow] = av.x; As[lk + 1][lrow] = av.y;
        As[lk + 2][lrow] = av.z; As[lk + 3][lrow] = av.w;
        Bs[lk + 0][lrow] = bv.x; Bs[lk + 1][lrow] = bv.y;
        Bs[lk + 2][lrow] = bv.z; Bs[lk + 3][lrow] = bv.w;
        __syncthreads();
#pragma unroll
        for (int kk = 0; kk < 16; ++kk) {
            float4 a = *(const float4*)&As[kk][r0];
            float4 b = *(const float4*)&Bs[kk][c0];
            acc[0][0] += a.x * b.x; acc[0][1] += a.x * b.y; acc[0][2] += a.x * b.z; acc[0][3] += a.x * b.w;
            acc[1][0] += a.y * b.x; acc[1][1] += a.y * b.y; acc[1][2] += a.y * b.z; acc[1][3] += a.y * b.w;
            acc[2][0] += a.z * b.x; acc[2][1] += a.z * b.y; acc[2][2] += a.z * b.z; acc[2][3] += a.z * b.w;
            acc[3][0] += a.w * b.x; acc[3][1] += a.w * b.y; acc[3][2] += a.w * b.z; acc[3][3] += a.w * b.w;
        }
        xa += 16; wa += 16;
    }

    float4 wb = *(const float4*)(Wb + n0 + c0);
#pragma unroll
    for (int i = 0; i < 4; ++i) {
        float4 o;
        o.x = acc[i][0] + wb.x; o.y = acc[i][1] + wb.y;
        o.z = acc[i][2] + wb.z; o.w = acc[i][3] + wb.w;
        *(float4*)(out + (size_t)(m0 + r0 + i) * DIM + n0 + c0) = o;
    }
}

// ---------------------------------------------------------------------------
// Phase 2: persistent cooperative scan, U-slice resident in LDS.
// Round 8: per-wave decoupled sync.
//  - wave w now owns the CONTIGUOUS k-range [128w, 128w+128) -> it depends on
//    exactly 4 producer blocks (jg' = 4w..4w+3, 8 wave-flags).  Each wave
//    polls only ITS 8 flags and immediately issues its own loads: no
//    block-wide poll, no barrier C (3 barriers/step -> 2).  Early waves
//    compute while late producers finish -> straggler variance overlaps
//    compute instead of serializing after it.
//  - contiguous k makes staging conflict-free WITHOUT swizzle: chunk layout
//    [32 k][8 b]; read addrs (ksl*8+bt*4)+32j start at banks {0,4,..,28},
//    covering all 32 banks once (8-way jt broadcast = free).
//  - loads: 4 x global_load_dwordx4 sc0 sc1, wave-contiguous 1KB chunks.
//  - publish protocol unchanged (rounds 4-7 anchor): returning agent-scope
//    exchanges, per-wave waitcnt ack, then that wave's own flag.
//  - ordering: red[w] safe (wave can't pass barrier B of step t before the
//    readers arrived there); val safe (publishers enter barrier A of t+1
//    only after publishing); hbuf is wave-private; compiler fence stops the
//    h loads from hoisting above the poll.
// ---------------------------------------------------------------------------
__global__ __launch_bounds__(NTHR, 1) void rnn_scan3(
    const float* __restrict__ Uw,   // [j][k] original layout
    const float* __restrict__ Ub,
    const float* __restrict__ bias,
    float* __restrict__ out,        // [B][T][D] holds wx, overwritten; +hT tail
    float* __restrict__ h0,         // [bg][k][8] column-contiguous
    float* __restrict__ h1,         // [bg][k][8]
    unsigned* __restrict__ bar) {   // flags: [bg][jg*2+pubwave] spaced 64B, zeroed
    extern __shared__ float lds[];
    float* Ulds = lds;                    // [DIM][UPITCH], Ulds[k][c]=Uw[j0+c][k]
    float* red  = lds + LDS_U;            // [8 waves][256]
    float* val  = red + LDS_RED;          // [256]
    float* hbuf = val + LDS_VAL;          // [8 waves][256] single chunk buffer

    const int tid = threadIdx.x;
    const int bg = blockIdx.x & 7;
    const int jg = blockIdx.x >> 3;
    const int j0 = jg * JB;
    const int b0 = bg * BB;

    // one-time LDS fill of this block's U-slice (transposed to [k][j])
    {
        int c = tid & 31;
        int kc = (tid >> 5) << 6;  // 16 chunks of 64 k
        const float* src = Uw + (size_t)(j0 + c) * DIM + kc;
#pragma unroll
        for (int i = 0; i < 16; ++i) {
            float4 v = *(const float4*)(src + i * 4);
            int k = kc + i * 4;
            Ulds[(k + 0) * UPITCH + c] = v.x;
            Ulds[(k + 1) * UPITCH + c] = v.y;
            Ulds[(k + 2) * UPITCH + c] = v.z;
            Ulds[(k + 3) * UPITCH + c] = v.w;
        }
    }

    float cst = 0.f;
    if (tid < 256) {
        int jl = tid & 31;
        cst = Ub[j0 + jl] + bias[j0 + jl];
    }
    __syncthreads();

    const int ksl = tid & 3;
    const int jt  = (tid >> 2) & 7;
    const int bt  = (tid >> 5) & 1;
    const int w   = tid >> 6;
    const int ln  = tid & 63;

    // wave w's k-range: [128w, 128w+128).  Lane computes k = 128w + ksl + 4i.
    const float* uw_p0 = Ulds + (size_t)(128 * w + ksl) * UPITCH + jt * 4;
    const size_t colf = (size_t)bg * 8192;               // column float offset
    // lane's chunk-0 load: wave region floats [1024w, +1024), lane piece 16B
    const size_t lf0 = (size_t)w * 1024 + (size_t)ln * 4;
    float* hstg = hbuf + w * 256 + ln * 4;               // staging write slot
    const float* hrd = hbuf + w * 256 + ksl * 8 + bt * 4;  // staging read base
    unsigned* flagbase = bar + (size_t)bg * 1024;        // 4KB per column
    unsigned* myfp = flagbase + (size_t)(8 * w + (ln & 7)) * 16;  // wave's 8 deps

    ull junk = 0;

    for (int t = 0; t < SEQT; ++t) {
        const float* hc_col = ((t & 1) ? h1 : h0) + colf;
        float* hn_col = ((t & 1) ? h0 : h1) + colf;

        // prefetch this step's wx early (latency hidden behind poll + k-loop)
        float wxv = 0.f;
        size_t oidx = 0;
        if (tid < 256) {
            int jl = tid & 31, bl = tid >> 5;
            oidx = ((size_t)(b0 + bl) * SEQT + t) * DIM + (j0 + jl);
            wxv = out[oidx];
        }

        // per-wave sync: wait only for the 4 producer blocks this wave reads
        if (t > 0) {
            unsigned want = (unsigned)t;
            unsigned f;
            do {
                f = want;
                if (ln < 8)
                    f = __hip_atomic_load(myfp, __ATOMIC_RELAXED, __HIP_MEMORY_SCOPE_AGENT);
            } while (__ballot(f < want));
        }
        asm volatile("" ::: "memory");       // loads must not hoist above poll
        __builtin_amdgcn_sched_barrier(0);

        // 4 x 16B bypass loads: the wave's whole k-slice, zero redundancy
        const float* hp = hc_col + lf0;
        f4 hv0, hv1, hv2, hv3;
        asm volatile("global_load_dwordx4 %0, %1, off sc0 sc1" : "=v"(hv0) : "v"(hp));
        asm volatile("global_load_dwordx4 %0, %1, off sc0 sc1" : "=v"(hv1) : "v"(hp + 256));
        asm volatile("global_load_dwordx4 %0, %1, off sc0 sc1" : "=v"(hv2) : "v"(hp + 512));
        asm volatile("global_load_dwordx4 %0, %1, off sc0 sc1" : "=v"(hv3) : "v"(hp + 768));
        asm volatile("s_waitcnt vmcnt(0)"
                     : "+v"(hv0), "+v"(hv1), "+v"(hv2), "+v"(hv3)
                     :: "memory");
        __builtin_amdgcn_sched_barrier(0);

        float acc[4][4] = {};   // [jj][bb]
        const float* up = uw_p0;

#pragma unroll
        for (int li = 0; li < 4; ++li) {      // chunk li covers i = 8*li .. 8*li+7
            f4 hv = (li == 0) ? hv0 : (li == 1) ? hv1 : (li == 2) ? hv2 : hv3;
            asm volatile("" ::: "memory");    // order: prior chunk's reads before this write
            *(f4*)hstg = hv;                  // wave-private staging
            asm volatile("" ::: "memory");    // order: write before this chunk's reads
#pragma unroll
            for (int j = 0; j < 8; ++j) {     // i = 8*li + j, k = 128w + 32li + ksl + 4j
                float2 ua = *(const float2*)up;
                float2 ub = *(const float2*)(up + 2);
                f4 h4 = *(const f4*)(hrd + j * 32);
                acc[0][0] += ua.x * h4.x; acc[0][1] += ua.x * h4.y; acc[0][2] += ua.x * h4.z; acc[0][3] += ua.x * h4.w;
                acc[1][0] += ua.y * h4.x; acc[1][1] += ua.y * h4.y; acc[1][2] += ua.y * h4.z; acc[1][3] += ua.y * h4.w;
                acc[2][0] += ub.x * h4.x; acc[2][1] += ub.x * h4.y; acc[2][2] += ub.x * h4.z; acc[2][3] += ub.x * h4.w;
                acc[3][0] += ub.y * h4.x; acc[3][1] += ub.y * h4.y; acc[3][2] += ub.y * h4.z; acc[3][3] += ub.y * h4.w;
                up += 4 * UPITCH;
            }
        }

        // reduce the 4 in-wave k-slots (lane bits 0,1)
#pragma unroll
        for (int jj = 0; jj < 4; ++jj)
#pragma unroll
            for (int bb = 0; bb < 4; ++bb) {
                float v = acc[jj][bb];
                v += __shfl_xor(v, 1, 64);
                v += __shfl_xor(v, 2, 64);
                acc[jj][bb] = v;
            }
        if (ksl == 0) {
#pragma unroll
            for (int jj = 0; jj < 4; ++jj)
#pragma unroll
                for (int bb = 0; bb < 4; ++bb)
                    red[w * 256 + (bt * 4 + bb) * 32 + jt * 4 + jj] = acc[jj][bb];
        }
        __syncthreads();   // A

        if (tid < 256) {  // cross-wave reduce + tanh + out write (j-fast)
            float s = 0.f;
#pragma unroll
            for (int ww = 0; ww < 8; ++ww) s += red[ww * 256 + tid];
            float v = tanhf(wxv + s + cst);
            out[oidx] = v;
            val[tid] = v;
            if (t == SEQT - 1)
                out[(size_t)BATCH * SEQT * DIM + (size_t)(b0 + (tid >> 5)) * DIM + (j0 + (tid & 31))] = v;
        }
        __syncthreads();   // B

        if (tid < 128) {  // publish h_col[k][8] as returning 8B exchanges (waves 0,1)
            int jl = tid >> 2, m = tid & 3;
            F2U p;
            p.f[0] = val[(2 * m + 0) * 32 + jl];
            p.f[1] = val[(2 * m + 1) * 32 + jl];
            ull old = __hip_atomic_exchange(
                (ull*)hn_col + (size_t)(j0 + jl) * 4 + m,
                p.u, __ATOMIC_RELAXED, __HIP_MEMORY_SCOPE_AGENT);
            junk ^= old;  // force returning form; consumed after the loop

            if (t < SEQT - 1) {
                // wave-local: this wave's exchanges acked AT the coherent
                // point, then this wave's own flag.
                __builtin_amdgcn_s_waitcnt(0);
                if ((tid & 63) == 0)
                    __hip_atomic_store(flagbase + ((size_t)jg * 2 + (tid >> 6)) * 16,
                                       (unsigned)(t + 1),
                                       __ATOMIC_RELAXED, __HIP_MEMORY_SCOPE_AGENT);
            }
        }
        // no barrier C: waves proceed straight into step t+1's per-wave poll
    }

    // impossible (NaN-pair pattern tanh can never produce) — keeps the
    // exchange returns live so vmcnt acks are real coherent-point acks.
    if (junk == 0xFFF00001FFF00002ULL) out[0] = -1.0f;
}

// ---------------------------------------------------------------------------
extern "C" void kernel_launch(void* const* d_in, const int* in_sizes, int n_in,
                              void* d_out, int out_size, void* d_ws, size_t ws_size,
                              hipStream_t stream) {
    const float* x    = (const float*)d_in[0];
    const float* W_w  = (const float*)d_in[1];
    const float* W_b  = (const float*)d_in[2];
    const float* U_w  = (const float*)d_in[3];
    const float* U_b  = (const float*)d_in[4];
    const float* bias = (const float*)d_in[5];
    float* out = (float*)d_out;

    // ws: [0,64K) flags ; [64K, +256K) h0 ; then h1
    unsigned* bar = (unsigned*)d_ws;
    float* h0 = (float*)((char*)d_ws + 65536);
    float* h1 = h0 + (size_t)DIM * BATCH;

    hipMemsetAsync(d_ws, 0, 65536 + 2 * (size_t)DIM * BATCH * sizeof(float), stream);

    gemm_wx<<<dim3((32768 / 64) * (DIM / 64)), dim3(256), 0, stream>>>(x, W_w, W_b, out);

    static bool attr_done = false;
    if (!attr_done) {
        hipFuncSetAttribute((const void*)rnn_scan3,
                            hipFuncAttributeMaxDynamicSharedMemorySize, LDS_BYTES);
        attr_done = true;
    }

    void* args[] = {(void*)&U_w, (void*)&U_b, (void*)&bias,
                    (void*)&out, (void*)&h0, (void*)&h1, (void*)&bar};
    hipLaunchCooperativeKernel((void*)rnn_scan3, dim3(NBLK), dim3(NTHR), args,
                               LDS_BYTES, stream);
}